// Round 8
// baseline (100.201 us; speedup 1.0000x reference)
//
#include <hip/hip_runtime.h>
#include <hip/hip_bf16.h>
#include <math.h>
#include <stdint.h>

#define N 1024
#define D 512
#define MAXNEG 64
#define HALF_CNT (1u << 19)  // (N*N)/2 = 524288

typedef __attribute__((ext_vector_type(8))) short short8;  // 8 bf16 = 4 VGPR
typedef __attribute__((ext_vector_type(4))) float f32x4;

// ---------------------------------------------------------------------------
// Threefry-2x32-20, key = (0,1) (jax.random.key(1)). jax uniform(n,n) counter
// layout (original, non-partitionable): pair (f, f+HALF) produces
// noise[flat=f] = x0_out and noise[flat=f+HALF] = x1_out. Row i < 512 has
// f = i*N+j < 2^19, so ONE eval yields noise for rows i and i+512 at col j.
// Verified bit-exact on HW (rounds 3,4: absmax == 0.0).
// ---------------------------------------------------------------------------
__device__ __forceinline__ uint32_t rotl32(uint32_t x, uint32_t r) {
    return (x << r) | (x >> (32u - r));
}

__device__ __forceinline__ uint2 tf_pair(uint32_t f) {
    const uint32_t K0 = 0u, K1 = 1u;
    const uint32_t KS2 = 0x1BD11BDBu;  // 0x1BD11BDA ^ K0 ^ K1
    uint32_t x0 = f, x1 = f + HALF_CNT;
    x0 += K0; x1 += K1;
#define TFR(r) { x0 += x1; x1 = rotl32(x1, (r)); x1 ^= x0; }
    TFR(13) TFR(15) TFR(26) TFR(6)
    x0 += K1;  x1 += KS2 + 1u;
    TFR(17) TFR(29) TFR(16) TFR(24)
    x0 += KS2; x1 += K0 + 2u;
    TFR(13) TFR(15) TFR(26) TFR(6)
    x0 += K0;  x1 += K1 + 3u;
    TFR(17) TFR(29) TFR(16) TFR(24)
    x0 += K1;  x1 += KS2 + 4u;
    TFR(13) TFR(15) TFR(26) TFR(6)
    x0 += KS2; x1 += K0 + 5u;
#undef TFR
    return make_uint2(x0, x1);
}

__device__ __forceinline__ unsigned long long shflx_u64(unsigned long long v, int m) {
    unsigned lo = (unsigned)(v & 0xffffffffull);
    unsigned hi = (unsigned)(v >> 32);
    lo = __shfl_xor(lo, m, 64);
    hi = __shfl_xor(hi, m, 64);
    return ((unsigned long long)hi << 32) | (unsigned long long)lo;
}

__device__ __forceinline__ ushort f2bf(float x) {
    __hip_bfloat16 h = __float2bfloat16(x);
    return *(ushort*)&h;
}

__device__ __forceinline__ short8 to_frag(float4 a, float4 b) {
    short8 r;
    r[0] = (short)f2bf(a.x); r[1] = (short)f2bf(a.y);
    r[2] = (short)f2bf(a.z); r[3] = (short)f2bf(a.w);
    r[4] = (short)f2bf(b.x); r[5] = (short)f2bf(b.y);
    r[6] = (short)f2bf(b.z); r[7] = (short)f2bf(b.w);
    return r;
}

// ---------------------------------------------------------------------------
// K1: fused convert+GEMM. 256 blocks x 256 threads; each block one 64x64 tile,
// each wave a 32x32 quadrant (2x2 of 16x16x32 bf16 MFMA, full K).
// Loads f32 V straight from L2/L3, converts to bf16 fragments in registers
// (no prep kernel, no bf16 buffer). Operand layout: lane l holds row/col
// (l&15), k = (l>>4)*8 + e (contiguous). C/D: col = lane&15, row = (l>>4)*4+r.
// Diagonal tiles (bi==bj) also emit inv[i] = 1/sqrt(sim[i][i]) -- the MFMA
// diag IS ||bf16(v_i)||^2, making the cosine self-consistent in bf16.
// Block (0,0) re-inits the global accumulators every call (ws is re-poisoned).
// ---------------------------------------------------------------------------
__global__ __launch_bounds__(256) void k_gemm(const float* __restrict__ V,
                                              float* __restrict__ sim,
                                              float* __restrict__ inv,
                                              float* __restrict__ gsum,
                                              float* __restrict__ gcnt,
                                              unsigned* __restrict__ done) {
    if (blockIdx.x == 0 && blockIdx.y == 0 && threadIdx.x == 0) {
        *gsum = 0.0f; *gcnt = 0.0f; *done = 0u;
    }
    const int t  = threadIdx.x;
    const int w  = t >> 6, l = t & 63;
    const int wr = w >> 1, wc = w & 1;
    const int lr = l & 15, lk = (l >> 4) * 8;
    const int bi = blockIdx.y, bj = blockIdx.x;

    const float* A0 = V + (size_t)(bi * 64 + wr * 32 + lr) * D + lk;
    const float* B0 = V + (size_t)(bj * 64 + wc * 32 + lr) * D + lk;

    f32x4 acc[2][2];
#pragma unroll
    for (int m = 0; m < 2; ++m)
#pragma unroll
        for (int n = 0; n < 2; ++n) acc[m][n] = (f32x4){0.f, 0.f, 0.f, 0.f};

    float4 cA[2][2], cB[2][2];
#pragma unroll
    for (int m = 0; m < 2; ++m) {
        cA[m][0] = *(const float4*)(A0 + (size_t)m * 16 * D);
        cA[m][1] = *(const float4*)(A0 + (size_t)m * 16 * D + 4);
        cB[m][0] = *(const float4*)(B0 + (size_t)m * 16 * D);
        cB[m][1] = *(const float4*)(B0 + (size_t)m * 16 * D + 4);
    }

    for (int k0 = 0; k0 < D; k0 += 32) {
        const bool more = (k0 + 32) < D;
        float4 nA[2][2], nB[2][2];
        if (more) {  // prefetch next K-step; lands during cvt+MFMA
#pragma unroll
            for (int m = 0; m < 2; ++m) {
                nA[m][0] = *(const float4*)(A0 + (size_t)m * 16 * D + k0 + 32);
                nA[m][1] = *(const float4*)(A0 + (size_t)m * 16 * D + k0 + 36);
                nB[m][0] = *(const float4*)(B0 + (size_t)m * 16 * D + k0 + 32);
                nB[m][1] = *(const float4*)(B0 + (size_t)m * 16 * D + k0 + 36);
            }
        }
        short8 a[2], b[2];
#pragma unroll
        for (int m = 0; m < 2; ++m) {
            a[m] = to_frag(cA[m][0], cA[m][1]);
            b[m] = to_frag(cB[m][0], cB[m][1]);
        }
#pragma unroll
        for (int m = 0; m < 2; ++m)
#pragma unroll
            for (int n = 0; n < 2; ++n)
                acc[m][n] = __builtin_amdgcn_mfma_f32_16x16x32_bf16(a[m], b[n], acc[m][n], 0, 0, 0);
        if (more) {
#pragma unroll
            for (int m = 0; m < 2; ++m) {
                cA[m][0] = nA[m][0]; cA[m][1] = nA[m][1];
                cB[m][0] = nB[m][0]; cB[m][1] = nB[m][1];
            }
        }
    }

    const int r0 = (l >> 4) * 4;
#pragma unroll
    for (int m = 0; m < 2; ++m) {
#pragma unroll
        for (int r = 0; r < 4; ++r) {
            const int grow = bi * 64 + wr * 32 + m * 16 + r0 + r;
            float* dst = sim + (size_t)grow * N + bj * 64 + wc * 32 + lr;
            dst[0]  = acc[m][0][r];
            dst[16] = acc[m][1][r];
        }
    }
    // diagonal: emit inv = 1/sqrt(||bf16(v)||^2). Lanes where (lr>>2)==(l>>4)
    // hold elements with row==col (r = lr&3).
    if (bi == bj && wr == wc && (lr >> 2) == (l >> 4)) {
        const int r = lr & 3;
#pragma unroll
        for (int m = 0; m < 2; ++m) {
            const int grow = bi * 64 + wr * 32 + m * 16 + r0 + r;
            inv[grow] = 1.0f / sqrtf(acc[m][m][r]);
        }
    }
}

// ---------------------------------------------------------------------------
// K2: paired per-row loss (HW-validated bit-exact machinery, rounds 3-4).
// Block b handles rows i0=b, i1=b+512 (shared Threefry evals: x0->i0, x1->i1).
// inv_i*inv_j scaling applied at row load (GEMM stores raw bf16 dots).
//  phase 1: load+scale sim rows; keys + per-row 256-bucket histogram
//  phase 2a: block suffix-scan -> threshold bucket B, remainder r (per row)
//  phase 2b: parallel select bucket>B (set semantics); boundary bucket -> list
//  phase 2c: serial top-r in boundary bucket (wave 0 <- row0, wave 1 <- row1)
//  phase 3: sum softplus(ns-ps) = log prod(1 + e^ns * e^-ps); ei=0 for invalid
//           slots keeps prod exactly 1.0 -> log exactly 0 (bit-exact masking)
//  final: last-block folds the mean (atomic RMW readback for XCD coherence).
// ---------------------------------------------------------------------------
__global__ __launch_bounds__(256) void k_rowloss(const float* __restrict__ sim,
                                                 const float* __restrict__ inv,
                                                 const int* __restrict__ labels,
                                                 float* __restrict__ gsum,
                                                 float* __restrict__ gcnt,
                                                 unsigned* __restrict__ done,
                                                 float* __restrict__ out) {
    __shared__ __align__(16) float simrow0[N];
    __shared__ __align__(16) float simrow1[N];
    __shared__ int   hist0[256], hist1[256];
    __shared__ unsigned long long list0[256], list1[256];
    __shared__ float ens0[MAXNEG], ens1[MAXNEG];
    __shared__ int   wpart0[4], wpart1[4];
    __shared__ float wsA[4], wsB[4];
    __shared__ int   wpA[4], wpB[4];
    __shared__ int   s_B0, s_r0, s_cnt0, s_lcnt0;
    __shared__ int   s_B1, s_r1, s_cnt1, s_lcnt1;

    const int b = blockIdx.x;
    const int i0 = b, i1 = b + 512;
    const int t = threadIdx.x;
    const int lane = t & 63, w = t >> 6;
    const int jb = t * 4;

    if (t == 0) {
        s_B0 = -1; s_r0 = 0; s_cnt0 = 0; s_lcnt0 = 0;
        s_B1 = -1; s_r1 = 0; s_cnt1 = 0; s_lcnt1 = 0;
    }
    hist0[t] = 0; hist1[t] = 0;

    // ---- phase 1: load + scale rows into LDS ----
    {
        const float invi0 = inv[i0], invi1 = inv[i1];
        float4 s0 = ((const float4*)(sim + (size_t)i0 * N))[t];
        float4 s1 = ((const float4*)(sim + (size_t)i1 * N))[t];
        float4 iv = ((const float4*)inv)[t];
        s0.x *= invi0 * iv.x; s0.y *= invi0 * iv.y;
        s0.z *= invi0 * iv.z; s0.w *= invi0 * iv.w;
        s1.x *= invi1 * iv.x; s1.y *= invi1 * iv.y;
        s1.z *= invi1 * iv.z; s1.w *= invi1 * iv.w;
        ((float4*)simrow0)[t] = s0;
        ((float4*)simrow1)[t] = s1;
    }
    const int labi0 = labels[i0], labi1 = labels[i1];
    int4 lv = ((const int4*)labels)[t];
    const int ljs[4] = {lv.x, lv.y, lv.z, lv.w};

    int npos0 = 0, npos1 = 0;
    unsigned long long kq0[4], kq1[4];
    __syncthreads();  // hist zero + s_* init visible before atomics
#pragma unroll
    for (int q = 0; q < 4; ++q) {
        const int j = jb + q;
        const uint2 rb = tf_pair((uint32_t)(i0 * N + j));
        const bool eq0 = (ljs[q] == labi0), eq1 = (ljs[q] == labi1);
        npos0 += (eq0 && j != i0) ? 1 : 0;
        npos1 += (eq1 && j != i1) ? 1 : 0;
        unsigned long long key0 = 0ull, key1 = 0ull;
        if (!eq0) {  // (value desc, index asc); valid keys >= 1024 > 0
            key0 = ((unsigned long long)(rb.x >> 9) << 11)
                 | (unsigned long long)(2047 - j);
            atomicAdd(&hist0[(int)(key0 >> 26)], 1);
        }
        if (!eq1) {
            key1 = ((unsigned long long)(rb.y >> 9) << 11)
                 | (unsigned long long)(2047 - j);
            atomicAdd(&hist1[(int)(key1 >> 26)], 1);
        }
        kq0[q] = key0; kq1[q] = key1;
    }
    __syncthreads();

    // ---- phase 2a: two suffix scans (bucket 255-t), block-wide ----
    {
        const int own0 = hist0[255 - t], own1 = hist1[255 - t];
        int v0 = own0, v1 = own1;
#pragma unroll
        for (int off = 1; off < 64; off <<= 1) {
            const int u0 = __shfl_up(v0, off, 64);
            const int u1 = __shfl_up(v1, off, 64);
            if (lane >= off) { v0 += u0; v1 += u1; }
        }
        if (lane == 63) { wpart0[w] = v0; wpart1[w] = v1; }
        __syncthreads();
        int add0 = 0, add1 = 0;
#pragma unroll
        for (int k = 0; k < 4; ++k) {
            add0 += (k < w) ? wpart0[k] : 0;
            add1 += (k < w) ? wpart1[k] : 0;
        }
        v0 += add0; v1 += add1;  // S[b], b = 255 - t
        if (v0 >= MAXNEG && v0 - own0 < MAXNEG) { s_B0 = 255 - t; s_r0 = MAXNEG - (v0 - own0); }
        if (v1 >= MAXNEG && v1 - own1 < MAXNEG) { s_B1 = 255 - t; s_r1 = MAXNEG - (v1 - own1); }
    }
    __syncthreads();

    // ---- phase 2b: parallel above-threshold select; collect boundary bucket --
    const int B0 = s_B0, B1 = s_B1;
#pragma unroll
    for (int q = 0; q < 4; ++q) {
        const unsigned long long key0 = kq0[q], key1 = kq1[q];
        if (key0 != 0ull) {
            const int bk = (int)(key0 >> 26);
            if (bk > B0) {
                const int slot = atomicAdd(&s_cnt0, 1);
                ens0[slot] = __expf(simrow0[2047 - (int)(key0 & 2047ull)] / 10.0f);
            } else if (bk == B0) {
                const int slot = atomicAdd(&s_lcnt0, 1);
                if (slot < 256) list0[slot] = key0;
            }
        }
        if (key1 != 0ull) {
            const int bk = (int)(key1 >> 26);
            if (bk > B1) {
                const int slot = atomicAdd(&s_cnt1, 1);
                ens1[slot] = __expf(simrow1[2047 - (int)(key1 & 2047ull)] / 10.0f);
            } else if (bk == B1) {
                const int slot = atomicAdd(&s_lcnt1, 1);
                if (slot < 256) list1[slot] = key1;
            }
        }
    }
    __syncthreads();

    // ---- phase 2c: serial top-r in boundary bucket; wave w handles row w ----
    if (w < 2) {
        const int rr = (w == 0) ? s_r0 : s_r1;
        if (rr > 0) {
            const unsigned long long* lst = (w == 0) ? list0 : list1;
            const int   m    = min((w == 0) ? s_lcnt0 : s_lcnt1, 256);
            const int   base = (w == 0) ? s_cnt0 : s_cnt1;
            float*      ensw = (w == 0) ? ens0 : ens1;
            const float* srw = (w == 0) ? simrow0 : simrow1;
            unsigned long long lk[4];
#pragma unroll
            for (int q = 0; q < 4; ++q) {
                const int idx = lane + q * 64;
                lk[q] = (idx < m) ? lst[idx] : 0ull;
            }
            for (int it = 0; it < rr; ++it) {
                unsigned long long mx = lk[0];
#pragma unroll
                for (int q = 1; q < 4; ++q) mx = lk[q] > mx ? lk[q] : mx;
#pragma unroll
                for (int off = 1; off < 64; off <<= 1) {
                    const unsigned long long o = shflx_u64(mx, off);
                    mx = o > mx ? o : mx;
                }
#pragma unroll
                for (int q = 0; q < 4; ++q) if (lk[q] == mx) lk[q] = 0ull;
                if (lane == 0)
                    ensw[base + it] = __expf(srw[2047 - (int)(mx & 2047ull)] / 10.0f);
            }
        }
    }
    __syncthreads();
    const int nneg0 = s_cnt0 + s_r0;  // == min(64, #negatives of row i0)
    const int nneg1 = s_cnt1 + s_r1;

    // ---- phase 3: product-form pair accumulation (both rows) ----
    float ei0[4], ei1[4];
#pragma unroll
    for (int q = 0; q < 4; ++q) {
        const int j = jb + q;
        ei0[q] = (ljs[q] == labi0 && j != i0) ? __expf(-simrow0[j] / 5.0f) : 0.0f;
        ei1[q] = (ljs[q] == labi1 && j != i1) ? __expf(-simrow1[j] / 5.0f) : 0.0f;
    }
    float p00 = 1.0f, p01 = 1.0f, p02 = 1.0f, p03 = 1.0f;
#pragma unroll 8
    for (int k = 0; k < nneg0; ++k) {
        const float e = ens0[k];
        p00 *= fmaf(e, ei0[0], 1.0f);
        p01 *= fmaf(e, ei0[1], 1.0f);
        p02 *= fmaf(e, ei0[2], 1.0f);
        p03 *= fmaf(e, ei0[3], 1.0f);
    }
    float p10 = 1.0f, p11 = 1.0f, p12 = 1.0f, p13 = 1.0f;
#pragma unroll 8
    for (int k = 0; k < nneg1; ++k) {
        const float e = ens1[k];
        p10 *= fmaf(e, ei1[0], 1.0f);
        p11 *= fmaf(e, ei1[1], 1.0f);
        p12 *= fmaf(e, ei1[2], 1.0f);
        p13 *= fmaf(e, ei1[3], 1.0f);
    }
    float r0 = __logf(p00) + __logf(p01) + __logf(p02) + __logf(p03);
    float r1 = __logf(p10) + __logf(p11) + __logf(p12) + __logf(p13);

#pragma unroll
    for (int off = 32; off > 0; off >>= 1) {
        r0 += __shfl_xor(r0, off, 64);
        r1 += __shfl_xor(r1, off, 64);
        npos0 += __shfl_xor(npos0, off, 64);
        npos1 += __shfl_xor(npos1, off, 64);
    }
    if (lane == 0) { wsA[w] = r0; wsB[w] = r1; wpA[w] = npos0; wpB[w] = npos1; }
    __syncthreads();
    if (t == 0) {
        const float rs0 = wsA[0] + wsA[1] + wsA[2] + wsA[3];
        const float rs1 = wsB[0] + wsB[1] + wsB[2] + wsB[3];
        const int   np0 = wpA[0] + wpA[1] + wpA[2] + wpA[3];
        const int   np1 = wpB[0] + wpB[1] + wpB[2] + wpB[3];
        const float rl0 = (np0 > 0) ? rs0 / fmaxf((float)np0 * (float)nneg0, 1.0f) : 0.0f;
        const float rl1 = (np1 > 0) ? rs1 / fmaxf((float)np1 * (float)nneg1, 1.0f) : 0.0f;
        const float hp  = (np0 > 0 ? 1.0f : 0.0f) + (np1 > 0 ? 1.0f : 0.0f);
        atomicAdd(gsum, rl0 + rl1);
        atomicAdd(gcnt, hp);
        __threadfence();
        const unsigned old = atomicAdd(done, 1u);
        if (old == (N / 2) - 1) {  // last block: coherent readback via atomic RMW
            const float Sv = atomicAdd(gsum, 0.0f);
            const float Cv = atomicAdd(gcnt, 0.0f);
            out[0] = (Cv > 0.0f) ? Sv / fmaxf(Cv, 1.0f) : 0.0f;
        }
    }
}

extern "C" void kernel_launch(void* const* d_in, const int* in_sizes, int n_in,
                              void* d_out, int out_size, void* d_ws, size_t ws_size,
                              hipStream_t stream) {
    const float* V      = (const float*)d_in[0];
    const int*   labels = (const int*)d_in[1];
    float* out = (float*)d_out;

    char* ws = (char*)d_ws;
    float*    inv  = (float*)(ws);                 // 4 KB
    float*    gsum = (float*)(ws + 4096);
    float*    gcnt = (float*)(ws + 4096 + 16);
    unsigned* done = (unsigned*)(ws + 4096 + 32);
    float*    sim  = (float*)(ws + 8192);          // 4 MB raw bf16 dots

    k_gemm   <<<dim3(N / 64, N / 64), 256, 0, stream>>>(V, sim, inv, gsum, gcnt, done);
    k_rowloss<<<N / 2, 256, 0, stream>>>(sim, inv, labels, gsum, gcnt, done, out);
}